// Round 8
// baseline (299.316 us; speedup 1.0000x reference)
//
#include <hip/hip_runtime.h>

// MS-SSIM loss, 5 levels, fused per-level kernel.
// R8: two stall-killers on top of R7 (R7: spread atomics 1093->298us total):
//  1) slots spread across 256 CACHE LINES (stride 64 B). R7's 256 floats
//     spanned only 16 lines -> ~45us of cross-XCD line-ownership chain.
//  2) avg-pool moved AFTER phase V: its global stores no longer sit before
//     the mid-kernel __syncthreads, whose s_waitcnt vmcnt(0) was draining
//     store acks for every wave (m97-style barrier drain).
// Carried (counter-verified): pitch-62 row-major LDS (conflicts 1.7e6),
// 32,240 B -> 5 blk/CU; __launch_bounds__(256,4) (bound 5 => 48-reg cap =>
// spill, R5); padded pyramid + zpad row-select (uniform float4 path);
// no early load issue (R4 pathology); TH=8 for levels 3-4.

#define TW 64
#define NIMG 48                // 16 * 3
#define HPITCH 62              // even (float2-aligned), bank step 30 mod 32
#define NSLOT 256              // spread-atomic slots per level
#define SSTRIDE 16             // floats between slots = 64 B -> 1 line/slot

template <int TH>
__global__ __launch_bounds__(256, 4) void ssim_level_kernel(
    const float* __restrict__ x, const float* __restrict__ y,
    long imgStride, int rowStride,
    float* __restrict__ dsx, float* __restrict__ dsy,
    long dsImgStride, int dsRowStride,
    const float* __restrict__ zpad,
    float* __restrict__ slots, int H, int W, int pad, int do_ds)
{
    constexpr int HHALO = TH + 10;
    constexpr int PLANE = HHALO * HPITCH;

    const float G[11] = {
        0.00102839f, 0.00759877f, 0.03600077f, 0.10936069f, 0.21300539f,
        0.26601173f, 0.21300539f, 0.10936069f, 0.03600077f, 0.00759877f,
        0.00102839f};
    const float C1 = 4.0e-4f;
    const float C2 = 3.6e-3f;

    __shared__ __align__(16) float hfT[5 * PLANE]; // TH=16: 32,240 B

    const int t   = threadIdx.x;
    const int img = blockIdx.z;
    const int C0  = blockIdx.x * TW;
    const int R0  = blockIdx.y * TH;
    const float* xi = x + (long)img * imgStride;
    const float* yi = y + (long)img * imgStride;

    // ---- Phase H: HHALO rows x 8 col-octets, r-major lanes ----
    if (t < HHALO * (TW / 8)) {
        const int r  = t % HHALO;
        const int q  = t / HHALO;
        const int gr = R0 + r - 5;
        const bool rok = ((unsigned)gr < (unsigned)H);
        const int gc0 = C0 + (q << 3) - 8;     // taps use [gc0+3, gc0+21)
        const bool fastp = pad || ((C0 >= 8) && (C0 + TW + 8 <= W)); // block-uniform

        float xv[24], yv[24];
        if (fastp) {
            const float* px = rok ? (xi + (long)gr * rowStride + gc0) : zpad;
            const float* py = rok ? (yi + (long)gr * rowStride + gc0) : zpad;
#pragma unroll
            for (int v = 0; v < 6; ++v) {
                const float4 a = reinterpret_cast<const float4*>(px)[v];
                const float4 b = reinterpret_cast<const float4*>(py)[v];
                xv[4 * v + 0] = a.x; xv[4 * v + 1] = a.y;
                xv[4 * v + 2] = a.z; xv[4 * v + 3] = a.w;
                yv[4 * v + 0] = b.x; yv[4 * v + 1] = b.y;
                yv[4 * v + 2] = b.z; yv[4 * v + 3] = b.w;
            }
        } else {
            const float* xrow = xi + (long)gr * rowStride;
            const float* yrow = yi + (long)gr * rowStride;
#pragma unroll
            for (int k = 3; k < 21; ++k) {
                const int gc = gc0 + k;
                const bool ok = rok && ((unsigned)gc < (unsigned)W);
                xv[k] = ok ? xrow[gc] : 0.0f;
                yv[k] = ok ? yrow[gc] : 0.0f;
            }
        }

        float xx[18], yy[18], xy[18];
#pragma unroll
        for (int k = 0; k < 18; ++k) {
            const float a = xv[k + 3], b = yv[k + 3];
            xx[k] = a * a; yy[k] = b * b; xy[k] = a * b;
        }

        float hx[8], hy[8], hxx[8], hyy[8], hxy[8];
#pragma unroll
        for (int j = 0; j < 8; ++j) {
            float sx = 0.f, sy = 0.f, sxx = 0.f, syy = 0.f, sxy = 0.f;
#pragma unroll
            for (int k = 0; k < 11; ++k) {
                const float g = G[k];
                sx  = fmaf(g, xv[j + k + 3], sx);
                sy  = fmaf(g, yv[j + k + 3], sy);
                sxx = fmaf(g, xx[j + k], sxx);
                syy = fmaf(g, yy[j + k], syy);
                sxy = fmaf(g, xy[j + k], sxy);
            }
            hx[j] = sx; hy[j] = sy; hxx[j] = sxx; hyy[j] = syy; hxy[j] = sxy;
        }
        float* hp = &hfT[r * HPITCH + (q << 3)];  // even word offset -> b64 ok
#pragma unroll
        for (int p = 0; p < 4; ++p) {
            reinterpret_cast<float2*>(hp + 0 * PLANE)[p] = make_float2(hx[2*p],  hx[2*p+1]);
            reinterpret_cast<float2*>(hp + 1 * PLANE)[p] = make_float2(hy[2*p],  hy[2*p+1]);
            reinterpret_cast<float2*>(hp + 2 * PLANE)[p] = make_float2(hxx[2*p], hxx[2*p+1]);
            reinterpret_cast<float2*>(hp + 3 * PLANE)[p] = make_float2(hyy[2*p], hyy[2*p+1]);
            reinterpret_cast<float2*>(hp + 4 * PLANE)[p] = make_float2(hxy[2*p], hxy[2*p+1]);
        }
    }
    __syncthreads();   // only lgkmcnt pending: no global stores before here

    // ---- Phase V: thread = (col, row strip of TH/4); scalar column reads ----
    const int c   = t & 63;
    const int rr0 = (t >> 6) * (TH / 4);     // wave-uniform
    float acc[5][TH / 4];
#pragma unroll
    for (int f = 0; f < 5; ++f) {
        const float* hp = &hfT[f * PLANE + rr0 * HPITCH + c];
        float hv[10 + TH / 4];
#pragma unroll
        for (int k = 0; k < 10 + TH / 4; ++k) hv[k] = hp[k * HPITCH];
#pragma unroll
        for (int i = 0; i < TH / 4; ++i) {
            float a = 0.f;
#pragma unroll
            for (int k = 0; k < 11; ++k) a = fmaf(G[k], hv[i + k], a);
            acc[f][i] = a;
        }
    }

    float local = 0.f;
    const int gc = C0 + c;
#pragma unroll
    for (int i = 0; i < TH / 4; ++i) {
        const int gr2 = R0 + rr0 + i;
        if (gr2 < H && gc < W) {
            const float mu1 = acc[0][i], mu2 = acc[1][i];
            const float mu1s = mu1 * mu1, mu2s = mu2 * mu2, m12 = mu1 * mu2;
            const float s1  = acc[2][i] - mu1s;
            const float s2  = acc[3][i] - mu2s;
            const float s12 = acc[4][i] - m12;
            const float num = (2.f * m12 + C1) * (2.f * s12 + C2);
            const float den = (mu1s + mu2s + C1) * (s1 + s2 + C2);
            local += num * __builtin_amdgcn_rcpf(den + 1e-8f);
        }
    }

    // ---- wave reduce -> one atomicAdd per wave into its own cache line ----
#pragma unroll
    for (int off = 32; off > 0; off >>= 1) local += __shfl_down(local, off, 64);
    if ((t & 63) == 0) {
        const int bid = (blockIdx.z * gridDim.y + blockIdx.y) * gridDim.x + blockIdx.x;
        const int slot = ((bid << 2) | (t >> 6)) & (NSLOT - 1);
        atomicAdd(slots + slot * SSTRIDE, local);
    }

    // ---- fused avg-pool 2x2 for next level (tail: stores ack at wave end) ----
    if (do_ds) {
        const int dsW = W >> 1, dsH = H >> 1;
        const int dr = t >> 5, dc = t & 31;
        const int gr2 = (R0 >> 1) + dr;
        const int gc2 = (C0 >> 1) + dc;
        if (dr < (TH >> 1) && gr2 < dsH && gc2 < dsW) {
            const float* sx = xi + (long)(2 * gr2) * rowStride + 2 * gc2;
            const float* sy = yi + (long)(2 * gr2) * rowStride + 2 * gc2;
            const float2 a0 = *reinterpret_cast<const float2*>(sx);
            const float2 a1 = *reinterpret_cast<const float2*>(sx + rowStride);
            const float2 b0 = *reinterpret_cast<const float2*>(sy);
            const float2 b1 = *reinterpret_cast<const float2*>(sy + rowStride);
            const long o = (long)img * dsImgStride + (long)gr2 * dsRowStride + gc2;
            dsx[o] = 0.25f * (a0.x + a0.y + a1.x + a1.y);
            dsy[o] = 0.25f * (b0.x + b0.y + b1.x + b1.y);
        }
    }
}

__global__ void finalize_kernel(const float* __restrict__ slots,
                                float* __restrict__ out)
{
    const int t = threadIdx.x;          // 256 threads: one slot per thread
    const float w[5] = {0.0448f, 0.2856f, 0.3001f, 0.2363f, 0.1333f};
    const float wsum = w[0] + w[1] + w[2] + w[3] + w[4];
    float acc = 0.f;
#pragma unroll
    for (int lvl = 0; lvl < 5; ++lvl) {
        const int d = 512 >> lvl;
        const float cnt = (float)NIMG * (float)d * (float)d;
        acc += (w[lvl] / wsum) / cnt * slots[(lvl * NSLOT + t) * SSTRIDE];
    }
#pragma unroll
    for (int off = 32; off > 0; off >>= 1) acc += __shfl_down(acc, off, 64);
    __shared__ float p[4];
    if ((t & 63) == 0) p[t >> 6] = acc;
    __syncthreads();
    if (t == 0) out[0] = 1.0f - (p[0] + p[1] + p[2] + p[3]);
}

extern "C" void kernel_launch(void* const* d_in, const int* in_sizes, int n_in,
                              void* d_out, int out_size, void* d_ws, size_t ws_size,
                              hipStream_t stream)
{
    const float* pred = (const float*)d_in[0];
    const float* targ = (const float*)d_in[1];
    float* out = (float*)d_out;
    float* ws  = (float*)d_ws;

    // padded pyramid: stride = W + 16 (8 zero cols each side)
    const long S1 = 256L * 272, S2 = 128L * 144, S3 = 64L * 80, S4 = 32L * 48;

    float* slots = ws;                      // 5 * 256 * 16 floats (80 KB)
    float* zpad  = slots + 5 * NSLOT * SSTRIDE;  // 640 zero floats
    float* x1 = zpad + 640;
    float* y1 = x1 + NIMG * S1;
    float* x2 = y1 + NIMG * S1;
    float* y2 = x2 + NIMG * S2;
    float* x3 = y2 + NIMG * S2;
    float* y3 = x3 + NIMG * S3;
    float* x4 = y3 + NIMG * S3;
    float* y4 = x4 + NIMG * S4;
    float* wsEnd = y4 + NIMG * S4 + 64;

    hipMemsetAsync(ws, 0, (size_t)(wsEnd - ws) * sizeof(float), stream);

    // level 0: unpadded harness input
    { dim3 g(8, 32, NIMG);
      ssim_level_kernel<16><<<g, 256, 0, stream>>>(pred, targ, 512L * 512, 512,
          x1 + 8, y1 + 8, S1, 272, zpad, slots + 0 * NSLOT * SSTRIDE, 512, 512, 0, 1); }
    // level 1
    { dim3 g(4, 16, NIMG);
      ssim_level_kernel<16><<<g, 256, 0, stream>>>(x1 + 8, y1 + 8, S1, 272,
          x2 + 8, y2 + 8, S2, 144, zpad, slots + 1 * NSLOT * SSTRIDE, 256, 256, 1, 1); }
    // level 2
    { dim3 g(2, 8, NIMG);
      ssim_level_kernel<16><<<g, 256, 0, stream>>>(x2 + 8, y2 + 8, S2, 144,
          x3 + 8, y3 + 8, S3, 80, zpad, slots + 2 * NSLOT * SSTRIDE, 128, 128, 1, 1); }
    // level 3: TH=8 -> 384 blocks
    { dim3 g(1, 8, NIMG);
      ssim_level_kernel<8><<<g, 256, 0, stream>>>(x3 + 8, y3 + 8, S3, 80,
          x4 + 8, y4 + 8, S4, 48, zpad, slots + 3 * NSLOT * SSTRIDE, 64, 64, 1, 1); }
    // level 4: TH=8 -> 192 blocks, no downsample
    { dim3 g(1, 4, NIMG);
      ssim_level_kernel<8><<<g, 256, 0, stream>>>(x4 + 8, y4 + 8, S4, 48,
          nullptr, nullptr, 0, 0, zpad, slots + 4 * NSLOT * SSTRIDE, 32, 32, 1, 0); }

    finalize_kernel<<<1, 256, 0, stream>>>(slots, out);
}

// Round 9
// 287.419 us; speedup vs baseline: 1.0414x; 1.0414x over previous
//
#include <hip/hip_runtime.h>

// MS-SSIM loss, 5 levels, fused per-level kernel.
// R9: (a) __launch_bounds__(256,3) -> ~84-reg cap: phase-H's 12 dwordx4 loads
//     + product arrays fit in regs -> one vmcnt window per strip (R8 analysis:
//     60-reg cap forced load/consume chunking -> exposed latency, VALU 38%).
//     LDS 32,240 B still caps at 5 blk/CU (5 waves/SIMD x 84 = 420 <= 512).
//     (b) pool back at HEAD (R7 ordering measured faster than R8 tail).
//     (c) memset shrunk 36 MB -> 82 KB: pool phase writes the 8-col zero pads
//     of the next level (edge blocks); zpad covers row-OOB.
//     (d) L2 uses TH=8 (1,536 blocks, 6/CU; was 768 @ 3/CU, latency-bound).
// Carried (counter-verified): pitch-62 row-major LDS (conflicts 1.7e6);
// spread atomics, 1 line/slot; padded pyramid + zpad row-select; no early
// load issue (R4); bound-5 => 48-reg spill (R5) -- never go below /3.

#define TW 64
#define NIMG 48                // 16 * 3
#define HPITCH 62              // even (float2-aligned), bank step 30 mod 32
#define NSLOT 256              // spread-atomic slots per level
#define SSTRIDE 16             // floats between slots = 64 B -> 1 line/slot

template <int TH>
__global__ __launch_bounds__(256, 3) void ssim_level_kernel(
    const float* __restrict__ x, const float* __restrict__ y,
    long imgStride, int rowStride,
    float* __restrict__ dsx, float* __restrict__ dsy,
    long dsImgStride, int dsRowStride,
    const float* __restrict__ zpad,
    float* __restrict__ slots, int H, int W, int pad, int do_ds)
{
    constexpr int HHALO = TH + 10;
    constexpr int PLANE = HHALO * HPITCH;

    const float G[11] = {
        0.00102839f, 0.00759877f, 0.03600077f, 0.10936069f, 0.21300539f,
        0.26601173f, 0.21300539f, 0.10936069f, 0.03600077f, 0.00759877f,
        0.00102839f};
    const float C1 = 4.0e-4f;
    const float C2 = 3.6e-3f;

    __shared__ __align__(16) float hfT[5 * PLANE]; // TH=16: 32,240 B

    const int t   = threadIdx.x;
    const int img = blockIdx.z;
    const int C0  = blockIdx.x * TW;
    const int R0  = blockIdx.y * TH;
    const float* xi = x + (long)img * imgStride;
    const float* yi = y + (long)img * imgStride;

    // ---- fused avg-pool 2x2 for next level (head position, R7) ----
    if (do_ds) {
        const int dsW = W >> 1, dsH = H >> 1;
        const int dr = t >> 5, dc = t & 31;
        const int gr2 = (R0 >> 1) + dr;
        const int gc2 = (C0 >> 1) + dc;
        const long dbase = (long)img * dsImgStride;
        if (dr < (TH >> 1) && gr2 < dsH && gc2 < dsW) {
            const float* sx = xi + (long)(2 * gr2) * rowStride + 2 * gc2;
            const float* sy = yi + (long)(2 * gr2) * rowStride + 2 * gc2;
            const float2 a0 = *reinterpret_cast<const float2*>(sx);
            const float2 a1 = *reinterpret_cast<const float2*>(sx + rowStride);
            const float2 b0 = *reinterpret_cast<const float2*>(sy);
            const float2 b1 = *reinterpret_cast<const float2*>(sy + rowStride);
            const long o = dbase + (long)gr2 * dsRowStride + gc2;
            dsx[o] = 0.25f * (a0.x + a0.y + a1.x + a1.y);
            dsy[o] = 0.25f * (b0.x + b0.y + b1.x + b1.y);
        }
        // write the 8-col zero pads of the next level (replaces big memset)
        if (dr < (TH >> 1) && gr2 < dsH && dc < 8) {
            if (blockIdx.x == 0) {
                const long o = dbase + (long)gr2 * dsRowStride + (dc - 8);
                dsx[o] = 0.0f; dsy[o] = 0.0f;
            }
            if (blockIdx.x == gridDim.x - 1) {
                const long o = dbase + (long)gr2 * dsRowStride + (dsW + dc);
                dsx[o] = 0.0f; dsy[o] = 0.0f;
            }
        }
    }

    // ---- Phase H: HHALO rows x 8 col-octets, r-major lanes ----
    if (t < HHALO * (TW / 8)) {
        const int r  = t % HHALO;
        const int q  = t / HHALO;
        const int gr = R0 + r - 5;
        const bool rok = ((unsigned)gr < (unsigned)H);
        const int gc0 = C0 + (q << 3) - 8;     // taps use [gc0+3, gc0+21)
        const bool fastp = pad || ((C0 >= 8) && (C0 + TW + 8 <= W)); // block-uniform

        float xv[24], yv[24];
        if (fastp) {
            const float* px = rok ? (xi + (long)gr * rowStride + gc0) : zpad;
            const float* py = rok ? (yi + (long)gr * rowStride + gc0) : zpad;
#pragma unroll
            for (int v = 0; v < 6; ++v) {
                const float4 a = reinterpret_cast<const float4*>(px)[v];
                const float4 b = reinterpret_cast<const float4*>(py)[v];
                xv[4 * v + 0] = a.x; xv[4 * v + 1] = a.y;
                xv[4 * v + 2] = a.z; xv[4 * v + 3] = a.w;
                yv[4 * v + 0] = b.x; yv[4 * v + 1] = b.y;
                yv[4 * v + 2] = b.z; yv[4 * v + 3] = b.w;
            }
        } else {
            const float* xrow = xi + (long)gr * rowStride;
            const float* yrow = yi + (long)gr * rowStride;
#pragma unroll
            for (int k = 3; k < 21; ++k) {
                const int gc = gc0 + k;
                const bool ok = rok && ((unsigned)gc < (unsigned)W);
                xv[k] = ok ? xrow[gc] : 0.0f;
                yv[k] = ok ? yrow[gc] : 0.0f;
            }
        }

        float xx[18], yy[18], xy[18];
#pragma unroll
        for (int k = 0; k < 18; ++k) {
            const float a = xv[k + 3], b = yv[k + 3];
            xx[k] = a * a; yy[k] = b * b; xy[k] = a * b;
        }

        float hx[8], hy[8], hxx[8], hyy[8], hxy[8];
#pragma unroll
        for (int j = 0; j < 8; ++j) {
            float sx = 0.f, sy = 0.f, sxx = 0.f, syy = 0.f, sxy = 0.f;
#pragma unroll
            for (int k = 0; k < 11; ++k) {
                const float g = G[k];
                sx  = fmaf(g, xv[j + k + 3], sx);
                sy  = fmaf(g, yv[j + k + 3], sy);
                sxx = fmaf(g, xx[j + k], sxx);
                syy = fmaf(g, yy[j + k], syy);
                sxy = fmaf(g, xy[j + k], sxy);
            }
            hx[j] = sx; hy[j] = sy; hxx[j] = sxx; hyy[j] = syy; hxy[j] = sxy;
        }
        float* hp = &hfT[r * HPITCH + (q << 3)];  // even word offset -> b64 ok
#pragma unroll
        for (int p = 0; p < 4; ++p) {
            reinterpret_cast<float2*>(hp + 0 * PLANE)[p] = make_float2(hx[2*p],  hx[2*p+1]);
            reinterpret_cast<float2*>(hp + 1 * PLANE)[p] = make_float2(hy[2*p],  hy[2*p+1]);
            reinterpret_cast<float2*>(hp + 2 * PLANE)[p] = make_float2(hxx[2*p], hxx[2*p+1]);
            reinterpret_cast<float2*>(hp + 3 * PLANE)[p] = make_float2(hyy[2*p], hyy[2*p+1]);
            reinterpret_cast<float2*>(hp + 4 * PLANE)[p] = make_float2(hxy[2*p], hxy[2*p+1]);
        }
    }
    __syncthreads();

    // ---- Phase V: thread = (col, row strip of TH/4); scalar column reads ----
    const int c   = t & 63;
    const int rr0 = (t >> 6) * (TH / 4);     // wave-uniform
    float acc[5][TH / 4];
#pragma unroll
    for (int f = 0; f < 5; ++f) {
        const float* hp = &hfT[f * PLANE + rr0 * HPITCH + c];
        float hv[10 + TH / 4];
#pragma unroll
        for (int k = 0; k < 10 + TH / 4; ++k) hv[k] = hp[k * HPITCH];
#pragma unroll
        for (int i = 0; i < TH / 4; ++i) {
            float a = 0.f;
#pragma unroll
            for (int k = 0; k < 11; ++k) a = fmaf(G[k], hv[i + k], a);
            acc[f][i] = a;
        }
    }

    float local = 0.f;
    const int gc = C0 + c;
#pragma unroll
    for (int i = 0; i < TH / 4; ++i) {
        const int gr2 = R0 + rr0 + i;
        if (gr2 < H && gc < W) {
            const float mu1 = acc[0][i], mu2 = acc[1][i];
            const float mu1s = mu1 * mu1, mu2s = mu2 * mu2, m12 = mu1 * mu2;
            const float s1  = acc[2][i] - mu1s;
            const float s2  = acc[3][i] - mu2s;
            const float s12 = acc[4][i] - m12;
            const float num = (2.f * m12 + C1) * (2.f * s12 + C2);
            const float den = (mu1s + mu2s + C1) * (s1 + s2 + C2);
            local += num * __builtin_amdgcn_rcpf(den + 1e-8f);
        }
    }

    // ---- wave reduce -> one atomicAdd per wave into its own cache line ----
#pragma unroll
    for (int off = 32; off > 0; off >>= 1) local += __shfl_down(local, off, 64);
    if ((t & 63) == 0) {
        const int bid = (blockIdx.z * gridDim.y + blockIdx.y) * gridDim.x + blockIdx.x;
        const int slot = ((bid << 2) | (t >> 6)) & (NSLOT - 1);
        atomicAdd(slots + slot * SSTRIDE, local);
    }
}

__global__ void finalize_kernel(const float* __restrict__ slots,
                                float* __restrict__ out)
{
    const int t = threadIdx.x;          // 256 threads: one slot per thread
    const float w[5] = {0.0448f, 0.2856f, 0.3001f, 0.2363f, 0.1333f};
    const float wsum = w[0] + w[1] + w[2] + w[3] + w[4];
    float acc = 0.f;
#pragma unroll
    for (int lvl = 0; lvl < 5; ++lvl) {
        const int d = 512 >> lvl;
        const float cnt = (float)NIMG * (float)d * (float)d;
        acc += (w[lvl] / wsum) / cnt * slots[(lvl * NSLOT + t) * SSTRIDE];
    }
#pragma unroll
    for (int off = 32; off > 0; off >>= 1) acc += __shfl_down(acc, off, 64);
    __shared__ float p[4];
    if ((t & 63) == 0) p[t >> 6] = acc;
    __syncthreads();
    if (t == 0) out[0] = 1.0f - (p[0] + p[1] + p[2] + p[3]);
}

extern "C" void kernel_launch(void* const* d_in, const int* in_sizes, int n_in,
                              void* d_out, int out_size, void* d_ws, size_t ws_size,
                              hipStream_t stream)
{
    const float* pred = (const float*)d_in[0];
    const float* targ = (const float*)d_in[1];
    float* out = (float*)d_out;
    float* ws  = (float*)d_ws;

    // padded pyramid: stride = W + 16 (8 zero cols each side)
    const long S1 = 256L * 272, S2 = 128L * 144, S3 = 64L * 80, S4 = 32L * 48;

    float* slots = ws;                      // 5 * 256 * 16 floats (80 KB)
    float* zpad  = slots + 5 * NSLOT * SSTRIDE;  // 640 zero floats
    float* x1 = zpad + 640;
    float* y1 = x1 + NIMG * S1;
    float* x2 = y1 + NIMG * S1;
    float* y2 = x2 + NIMG * S2;
    float* x3 = y2 + NIMG * S2;
    float* y3 = x3 + NIMG * S3;
    float* x4 = y3 + NIMG * S3;
    float* y4 = x4 + NIMG * S4;

    // zero only slots + zpad (pads of pyramid levels are written by pool phase)
    hipMemsetAsync(ws, 0, (size_t)(5 * NSLOT * SSTRIDE + 640) * sizeof(float), stream);

    // level 0: unpadded harness input
    { dim3 g(8, 32, NIMG);
      ssim_level_kernel<16><<<g, 256, 0, stream>>>(pred, targ, 512L * 512, 512,
          x1 + 8, y1 + 8, S1, 272, zpad, slots + 0 * NSLOT * SSTRIDE, 512, 512, 0, 1); }
    // level 1
    { dim3 g(4, 16, NIMG);
      ssim_level_kernel<16><<<g, 256, 0, stream>>>(x1 + 8, y1 + 8, S1, 272,
          x2 + 8, y2 + 8, S2, 144, zpad, slots + 1 * NSLOT * SSTRIDE, 256, 256, 1, 1); }
    // level 2: TH=8 -> 1536 blocks (6/CU; was 768 @ 3/CU latency-bound)
    { dim3 g(2, 16, NIMG);
      ssim_level_kernel<8><<<g, 256, 0, stream>>>(x2 + 8, y2 + 8, S2, 144,
          x3 + 8, y3 + 8, S3, 80, zpad, slots + 2 * NSLOT * SSTRIDE, 128, 128, 1, 1); }
    // level 3: TH=8 -> 384 blocks
    { dim3 g(1, 8, NIMG);
      ssim_level_kernel<8><<<g, 256, 0, stream>>>(x3 + 8, y3 + 8, S3, 80,
          x4 + 8, y4 + 8, S4, 48, zpad, slots + 3 * NSLOT * SSTRIDE, 64, 64, 1, 1); }
    // level 4: TH=8 -> 192 blocks, no downsample
    { dim3 g(1, 4, NIMG);
      ssim_level_kernel<8><<<g, 256, 0, stream>>>(x4 + 8, y4 + 8, S4, 48,
          nullptr, nullptr, 0, 0, zpad, slots + 4 * NSLOT * SSTRIDE, 32, 32, 1, 0); }

    finalize_kernel<<<1, 256, 0, stream>>>(slots, out);
}

// Round 10
// 283.302 us; speedup vs baseline: 1.0565x; 1.0145x over previous
//
#include <hip/hip_runtime.h>

// MS-SSIM loss, 5 levels, fused per-level kernel.
// R10: (a) TH=32 for L0/L1 -> 6,144/1,536 blocks. R7-R9 showed effective
//      residency pinned at ~2.5 blocks/CU regardless of LDS headroom ->
//      per-block fixed latency dominates; halve block count, cut vert-halo
//      redundancy 1.625->1.31. (b) packed fp32: (x,y) as float2 through
//      phase H+V -> v_pk_fma_f32 (conv insts -40%); LDS planes interleaved
//      float2 (b64 reads, conflict-free). (c) launch_bounds(256,2): cap 128
//      for the bigger live set (R5: cap<need => spill; watch WRITE_SIZE).
// Carried (counter-verified): spread atomics 1 line/slot (R7: 1093->298);
// row-major LDS pitch with bank-step 30 mod 32 (R3: conflicts 14x down);
// padded pyramid + zpad row-select; pool at head (R8: tail worse); tiny memset.

#define TW 64
#define NIMG 48
#define P2 63                  // float2 pitch, planes 01/23 (2*63=126==30 mod 32)
#define P1 62                  // float pitch, plane 4 (62==30 mod 32)
#define NSLOT 256
#define SSTRIDE 16             // 64 B between slots -> 1 cache line each

typedef float v2f __attribute__((ext_vector_type(2)));

template <int TH>
__global__ __launch_bounds__(256, 2) void ssim_level_kernel(
    const float* __restrict__ x, const float* __restrict__ y,
    long imgStride, int rowStride,
    float* __restrict__ dsx, float* __restrict__ dsy,
    long dsImgStride, int dsRowStride,
    const float* __restrict__ zpad,
    float* __restrict__ slots, int H, int W, int pad, int do_ds)
{
    constexpr int HHALO = TH + 10;
    constexpr int RPT   = TH / 4;          // rows per phase-V thread

    const float G[11] = {
        0.00102839f, 0.00759877f, 0.03600077f, 0.10936069f, 0.21300539f,
        0.26601173f, 0.21300539f, 0.10936069f, 0.03600077f, 0.00759877f,
        0.00102839f};
    const float C1 = 4.0e-4f;
    const float C2 = 3.6e-3f;

    __shared__ __align__(16) v2f   sm01[HHALO * P2];  // (hx,  hy )
    __shared__ __align__(16) v2f   sm23[HHALO * P2];  // (hxx, hyy)
    __shared__ __align__(16) float sm4 [HHALO * P1];  // hxy

    const int t   = threadIdx.x;
    const int img = blockIdx.z;
    const int C0  = blockIdx.x * TW;
    const int R0  = blockIdx.y * TH;
    const float* xi = x + (long)img * imgStride;
    const float* yi = y + (long)img * imgStride;

    // ---- fused avg-pool 2x2 for next level (head; writes next level's pads) ----
    if (do_ds) {
        const int dsW = W >> 1, dsH = H >> 1;
        const long dbase = (long)img * dsImgStride;
        for (int i = t; i < (TH / 2) * 32; i += 256) {
            const int dr = i >> 5, dc = i & 31;
            const int gr2 = (R0 >> 1) + dr;
            const int gc2 = (C0 >> 1) + dc;
            if (gr2 < dsH && gc2 < dsW) {
                const float* sx = xi + (long)(2 * gr2) * rowStride + 2 * gc2;
                const float* sy = yi + (long)(2 * gr2) * rowStride + 2 * gc2;
                const float2 a0 = *reinterpret_cast<const float2*>(sx);
                const float2 a1 = *reinterpret_cast<const float2*>(sx + rowStride);
                const float2 b0 = *reinterpret_cast<const float2*>(sy);
                const float2 b1 = *reinterpret_cast<const float2*>(sy + rowStride);
                const long o = dbase + (long)gr2 * dsRowStride + gc2;
                dsx[o] = 0.25f * (a0.x + a0.y + a1.x + a1.y);
                dsy[o] = 0.25f * (b0.x + b0.y + b1.x + b1.y);
            }
            if (gr2 < dsH && dc < 8) {    // zero the 8-col pads
                if (blockIdx.x == 0) {
                    const long o = dbase + (long)gr2 * dsRowStride + (dc - 8);
                    dsx[o] = 0.0f; dsy[o] = 0.0f;
                }
                if (blockIdx.x == gridDim.x - 1) {
                    const long o = dbase + (long)gr2 * dsRowStride + (dsW + dc);
                    dsx[o] = 0.0f; dsy[o] = 0.0f;
                }
            }
        }
    }

    // ---- Phase H: HHALO rows x 8 col-octets, r-major lanes ----
    const bool fastp = pad || ((C0 >= 8) && (C0 + TW + 8 <= W)); // block-uniform
    for (int s = t; s < HHALO * 8; s += 256) {
        const int r  = s % HHALO;
        const int q  = s / HHALO;
        const int gr = R0 + r - 5;
        const bool rok = ((unsigned)gr < (unsigned)H);
        const int gc0 = C0 + (q << 3) - 8;     // taps use [gc0+3, gc0+21)

        float xv[24], yv[24];
        if (fastp) {
            const float* px = rok ? (xi + (long)gr * rowStride + gc0) : zpad;
            const float* py = rok ? (yi + (long)gr * rowStride + gc0) : zpad;
#pragma unroll
            for (int v = 0; v < 6; ++v) {
                const float4 a = reinterpret_cast<const float4*>(px)[v];
                const float4 b = reinterpret_cast<const float4*>(py)[v];
                xv[4 * v + 0] = a.x; xv[4 * v + 1] = a.y;
                xv[4 * v + 2] = a.z; xv[4 * v + 3] = a.w;
                yv[4 * v + 0] = b.x; yv[4 * v + 1] = b.y;
                yv[4 * v + 2] = b.z; yv[4 * v + 3] = b.w;
            }
        } else {
            const float* xrow = xi + (long)gr * rowStride;
            const float* yrow = yi + (long)gr * rowStride;
#pragma unroll
            for (int k = 3; k < 21; ++k) {
                const int gc = gc0 + k;
                const bool ok = rok && ((unsigned)gc < (unsigned)W);
                xv[k] = ok ? xrow[gc] : 0.0f;
                yv[k] = ok ? yrow[gc] : 0.0f;
            }
        }

        v2f w2[18]; float xy[18];              // (x^2,y^2) packed, xy scalar
#pragma unroll
        for (int k = 0; k < 18; ++k) {
            const float a = xv[k + 3], b = yv[k + 3];
            v2f w; w.x = a * a; w.y = b * b;
            w2[k] = w; xy[k] = a * b;
        }

        const int cb = (q << 3);
#pragma unroll
        for (int j = 0; j < 8; ++j) {          // per-j conv, immediate LDS write
            v2f s01 = {0.f, 0.f}, s23 = {0.f, 0.f};
            float s4 = 0.f;
#pragma unroll
            for (int k = 0; k < 11; ++k) {
                const float g = G[k];
                v2f w; w.x = xv[j + k + 3]; w.y = yv[j + k + 3];
                s01 += w * g;                  // v_pk_fma_f32
                s23 += w2[j + k] * g;          // v_pk_fma_f32
                s4   = fmaf(g, xy[j + k], s4);
            }
            sm01[r * P2 + cb + j] = s01;
            sm23[r * P2 + cb + j] = s23;
            sm4 [r * P1 + cb + j] = s4;
        }
    }
    __syncthreads();

    // ---- Phase V: thread = (col, RPT-row strip); b64 column reads, pk conv ----
    const int c   = t & 63;
    const int rr0 = (t >> 6) * RPT;            // wave-uniform
    v2f acc01[RPT], acc23[RPT];
    float acc4[RPT];
    {
        v2f hv[RPT + 10];
#pragma unroll
        for (int k = 0; k < RPT + 10; ++k) hv[k] = sm01[(rr0 + k) * P2 + c];
#pragma unroll
        for (int i = 0; i < RPT; ++i) {
            v2f a = {0.f, 0.f};
#pragma unroll
            for (int k = 0; k < 11; ++k) a += hv[i + k] * G[k];
            acc01[i] = a;
        }
#pragma unroll
        for (int k = 0; k < RPT + 10; ++k) hv[k] = sm23[(rr0 + k) * P2 + c];
#pragma unroll
        for (int i = 0; i < RPT; ++i) {
            v2f a = {0.f, 0.f};
#pragma unroll
            for (int k = 0; k < 11; ++k) a += hv[i + k] * G[k];
            acc23[i] = a;
        }
    }
    {
        float hs[RPT + 10];
#pragma unroll
        for (int k = 0; k < RPT + 10; ++k) hs[k] = sm4[(rr0 + k) * P1 + c];
#pragma unroll
        for (int i = 0; i < RPT; ++i) {
            float a = 0.f;
#pragma unroll
            for (int k = 0; k < 11; ++k) a = fmaf(G[k], hs[i + k], a);
            acc4[i] = a;
        }
    }

    float local = 0.f;
    const int gc = C0 + c;
#pragma unroll
    for (int i = 0; i < RPT; ++i) {
        const int gr2 = R0 + rr0 + i;
        if (gr2 < H && gc < W) {
            const float mu1 = acc01[i].x, mu2 = acc01[i].y;
            const float mu1s = mu1 * mu1, mu2s = mu2 * mu2, m12 = mu1 * mu2;
            const float s1  = acc23[i].x - mu1s;
            const float s2  = acc23[i].y - mu2s;
            const float s12 = acc4[i] - m12;
            const float num = (2.f * m12 + C1) * (2.f * s12 + C2);
            const float den = (mu1s + mu2s + C1) * (s1 + s2 + C2);
            local += num * __builtin_amdgcn_rcpf(den + 1e-8f);
        }
    }

    // ---- wave reduce -> one atomicAdd per wave into its own cache line ----
#pragma unroll
    for (int off = 32; off > 0; off >>= 1) local += __shfl_down(local, off, 64);
    if ((t & 63) == 0) {
        const int bid = (blockIdx.z * gridDim.y + blockIdx.y) * gridDim.x + blockIdx.x;
        const int slot = ((bid << 2) | (t >> 6)) & (NSLOT - 1);
        atomicAdd(slots + slot * SSTRIDE, local);
    }
}

__global__ void finalize_kernel(const float* __restrict__ slots,
                                float* __restrict__ out)
{
    const int t = threadIdx.x;
    const float w[5] = {0.0448f, 0.2856f, 0.3001f, 0.2363f, 0.1333f};
    const float wsum = w[0] + w[1] + w[2] + w[3] + w[4];
    float acc = 0.f;
#pragma unroll
    for (int lvl = 0; lvl < 5; ++lvl) {
        const int d = 512 >> lvl;
        const float cnt = (float)NIMG * (float)d * (float)d;
        acc += (w[lvl] / wsum) / cnt * slots[(lvl * NSLOT + t) * SSTRIDE];
    }
#pragma unroll
    for (int off = 32; off > 0; off >>= 1) acc += __shfl_down(acc, off, 64);
    __shared__ float p[4];
    if ((t & 63) == 0) p[t >> 6] = acc;
    __syncthreads();
    if (t == 0) out[0] = 1.0f - (p[0] + p[1] + p[2] + p[3]);
}

extern "C" void kernel_launch(void* const* d_in, const int* in_sizes, int n_in,
                              void* d_out, int out_size, void* d_ws, size_t ws_size,
                              hipStream_t stream)
{
    const float* pred = (const float*)d_in[0];
    const float* targ = (const float*)d_in[1];
    float* out = (float*)d_out;
    float* ws  = (float*)d_ws;

    // padded pyramid: stride = W + 16 (8 zero cols each side)
    const long S1 = 256L * 272, S2 = 128L * 144, S3 = 64L * 80, S4 = 32L * 48;

    float* slots = ws;                      // 5 * 256 * 16 floats (80 KB)
    float* zpad  = slots + 5 * NSLOT * SSTRIDE;  // 640 zero floats
    float* x1 = zpad + 640;
    float* y1 = x1 + NIMG * S1;
    float* x2 = y1 + NIMG * S1;
    float* y2 = x2 + NIMG * S2;
    float* x3 = y2 + NIMG * S2;
    float* y3 = x3 + NIMG * S3;
    float* x4 = y3 + NIMG * S3;
    float* y4 = x4 + NIMG * S4;

    hipMemsetAsync(ws, 0, (size_t)(5 * NSLOT * SSTRIDE + 640) * sizeof(float), stream);

    // level 0: TH=32 -> 6,144 blocks
    { dim3 g(8, 16, NIMG);
      ssim_level_kernel<32><<<g, 256, 0, stream>>>(pred, targ, 512L * 512, 512,
          x1 + 8, y1 + 8, S1, 272, zpad, slots + 0 * NSLOT * SSTRIDE, 512, 512, 0, 1); }
    // level 1: TH=32 -> 1,536 blocks
    { dim3 g(4, 8, NIMG);
      ssim_level_kernel<32><<<g, 256, 0, stream>>>(x1 + 8, y1 + 8, S1, 272,
          x2 + 8, y2 + 8, S2, 144, zpad, slots + 1 * NSLOT * SSTRIDE, 256, 256, 1, 1); }
    // level 2: TH=8 -> 1,536 blocks
    { dim3 g(2, 16, NIMG);
      ssim_level_kernel<8><<<g, 256, 0, stream>>>(x2 + 8, y2 + 8, S2, 144,
          x3 + 8, y3 + 8, S3, 80, zpad, slots + 2 * NSLOT * SSTRIDE, 128, 128, 1, 1); }
    // level 3: TH=8 -> 384 blocks
    { dim3 g(1, 8, NIMG);
      ssim_level_kernel<8><<<g, 256, 0, stream>>>(x3 + 8, y3 + 8, S3, 80,
          x4 + 8, y4 + 8, S4, 48, zpad, slots + 3 * NSLOT * SSTRIDE, 64, 64, 1, 1); }
    // level 4: TH=8 -> 192 blocks, no downsample
    { dim3 g(1, 4, NIMG);
      ssim_level_kernel<8><<<g, 256, 0, stream>>>(x4 + 8, y4 + 8, S4, 48,
          nullptr, nullptr, 0, 0, zpad, slots + 4 * NSLOT * SSTRIDE, 32, 32, 1, 0); }

    finalize_kernel<<<1, 256, 0, stream>>>(slots, out);
}